// Round 1
// baseline (192.631 us; speedup 1.0000x reference)
//
#include <hip/hip_runtime.h>
#include <stdint.h>

// Bitwise reproducibility vs the numpy reference: forbid a*b+c fusion so every
// mul/add rounds exactly like the ref (keep-decision booleans must not flip).
#pragma clang fp contract(off)

typedef unsigned long long u64;

namespace {
constexpr int BB = 4;
constexpr int NN = 4096;
constexpr int CC = 64;
constexpr int BN = BB * NN;
constexpr float TARGET = 560.0f;
constexpr float MIN_BOX = 5.0f;
constexpr float IOU_THR = 0.2f;
constexpr float CONF_THR = 0.001f;
constexpr float BOX_CONF_THR = 0.01f;
constexpr float MAX_WH = 4096.0f;
constexpr int MAXK = 2048;   // per-(batch,class) capacity; data has ~64 +/- 8 per class
}

// ---------------- k1: clip boxes, conf = max_c(cls_pred*score), argmax, valid, sort key
__global__ void k1_score(const float* __restrict__ boxes,
                         const float* __restrict__ box_scores,
                         const float* __restrict__ cls_preds,
                         float4* __restrict__ boxes_c,
                         float* __restrict__ conf,
                         int* __restrict__ clsval,
                         u64* __restrict__ keys) {
    int t = blockIdx.x * blockDim.x + threadIdx.x;
    if (t >= BN) return;
    float4 bx = ((const float4*)boxes)[t];
    float x1 = fminf(fmaxf(bx.x, 0.0f), TARGET);
    float y1 = fminf(fmaxf(bx.y, 0.0f), TARGET);
    float x2 = fminf(fmaxf(bx.z, 0.0f), TARGET);
    float y2 = fminf(fmaxf(bx.w, 0.0f), TARGET);
    float w = x2 - x1, h = y2 - y1;
    float bs = box_scores[t];
    const float4* cp = (const float4*)(cls_preds + (size_t)t * CC);
    float best = -1.0f;   // products are >= 0, so first element always wins vs init
    int bestc = 0;
#pragma unroll
    for (int q = 0; q < CC / 4; ++q) {
        float4 v = cp[q];
        float p0 = v.x * bs, p1 = v.y * bs, p2 = v.z * bs, p3 = v.w * bs;
        // strict > preserves numpy first-occurrence argmax semantics
        if (p0 > best) { best = p0; bestc = q * 4 + 0; }
        if (p1 > best) { best = p1; bestc = q * 4 + 1; }
        if (p2 > best) { best = p2; bestc = q * 4 + 2; }
        if (p3 > best) { best = p3; bestc = q * 4 + 3; }
    }
    bool valid = (bs > BOX_CONF_THR) && (w > MIN_BOX) && (h > MIN_BOX) && (best > CONF_THR);
    float sk = valid ? best : -1.0f;
    // monotonic float->uint map (ascending); key = (map<<32) | ~idx so that a
    // DESCENDING u64 sort == stable descending sort by score (idx ascending on ties)
    unsigned fb = __float_as_uint(sk);
    unsigned mm = (fb & 0x80000000u) ? ~fb : (fb | 0x80000000u);
    int i = t & (NN - 1);
    keys[t] = ((u64)mm << 32) | (unsigned)(~(unsigned)i);
    float4 bc; bc.x = x1; bc.y = y1; bc.z = x2; bc.w = y2;
    boxes_c[t] = bc;
    conf[t] = best;
    clsval[t] = bestc | (valid ? 0x10000 : 0);
}

// ---------------- k2: per-batch bitonic sort (descending) of 4096 u64 keys in LDS,
// then gather sorted-order arrays: det rows, class-offset boxes, cls|valid, keep=0
__global__ __launch_bounds__(1024) void k2_sort(u64* __restrict__ keys,
                                                const float4* __restrict__ boxes_c,
                                                const float* __restrict__ conf,
                                                const int* __restrict__ clsval,
                                                float4* __restrict__ sobox,
                                                float* __restrict__ sdet,
                                                int* __restrict__ sclsv,
                                                int* __restrict__ keep) {
    __shared__ u64 sk[NN];   // 32 KB
    int b = blockIdx.x;
    int tid = threadIdx.x;
    const u64* kb = keys + (size_t)b * NN;
    for (int p = tid; p < NN; p += 1024) sk[p] = kb[p];
    for (int kk = 2; kk <= NN; kk <<= 1) {
        for (int j = kk >> 1; j > 0; j >>= 1) {
            __syncthreads();
            for (int e = tid; e < NN; e += 1024) {
                int pr = e ^ j;
                if (pr > e) {
                    u64 a = sk[e], c = sk[pr];
                    bool desc = ((e & kk) == 0);
                    if (desc ? (a < c) : (a > c)) { sk[e] = c; sk[pr] = a; }
                }
            }
        }
    }
    __syncthreads();
    for (int p = tid; p < NN; p += 1024) {
        u64 key = sk[p];
        unsigned idx = ~(unsigned)(key & 0xFFFFFFFFull);
        int src = b * NN + (int)idx;
        float4 bc = boxes_c[src];
        float cf = conf[src];
        int cv = clsval[src];
        int c = cv & 0xFF;
        int valid = (cv >> 16) & 1;
        float off = (float)c * MAX_WH;   // exact product; + is the ref's rounding
        float4 ob;
        ob.x = bc.x + off; ob.y = bc.y + off; ob.z = bc.z + off; ob.w = bc.w + off;
        int dst = b * NN + p;
        sobox[dst] = ob;
        float* dr = sdet + (size_t)dst * 8;
        dr[0] = bc.x; dr[1] = bc.y; dr[2] = bc.z; dr[3] = bc.w;
        dr[4] = cf;   dr[5] = (float)c; dr[6] = 0.0f; dr[7] = 0.0f;
        sclsv[dst] = c | (valid << 8);
        keep[dst] = 0;
    }
}

// ---------------- k3: one wave per (batch,class). Cross-class IoU is exactly 0
// (offset >= 4096 > any extent), so global greedy NMS == independent per-class greedy.
__global__ __launch_bounds__(64) void k3_nms(const float4* __restrict__ sobox,
                                             const int* __restrict__ sclsv,
                                             int* __restrict__ keep) {
    __shared__ float4 lbox[MAXK];   // 32 KB
    __shared__ int lpos[MAXK];      //  8 KB
    int b = blockIdx.x >> 6;        // / CC
    int myc = blockIdx.x & 63;      // % CC
    int lane = threadIdx.x;
    int base0 = b * NN;
    // ballot-compact this class's valid boxes, preserving sorted order
    int k = 0;
    for (int base = 0; base < NN; base += 64) {
        int p = base + lane;
        int cv = sclsv[base0 + p];
        bool pred = ((cv >> 8) != 0) && ((cv & 0xFF) == myc);
        u64 m = __ballot(pred);
        if (pred) {
            int ofs = __popcll(m & ((1ull << lane) - 1ull));
            int d = k + ofs;
            if (d < MAXK) { lbox[d] = sobox[base0 + p]; lpos[d] = p; }
        }
        k += (int)__popcll(m);
    }
    if (k > MAXK) k = MAXK;
    __syncthreads();
    // greedy: suppression bitmask distributed over lanes (lane w owns word w, k<=2048 -> w<32)
    u64 supw = 0;
    for (int i = 0; i < k; ++i) {
        int w = i >> 6, bit = i & 63;
        u64 wd = __shfl(supw, w);
        if (((wd >> bit) & 1ull) == 0ull) {
            if (lane == 0) keep[base0 + lpos[i]] = 1;
            float4 bi = lbox[i];
            float ai = (bi.z - bi.x) * (bi.w - bi.y);
            for (int jb = (i + 1) & ~63; jb < k; jb += 64) {
                int j = jb + lane;
                bool s = false;
                if (j > i && j < k) {
                    float4 bj = lbox[j];
                    float aj = (bj.z - bj.x) * (bj.w - bj.y);
                    float ltx = fmaxf(bi.x, bj.x);
                    float lty = fmaxf(bi.y, bj.y);
                    float rbx = fminf(bi.z, bj.z);
                    float rby = fminf(bi.w, bj.w);
                    float ww = fmaxf(rbx - ltx, 0.0f);
                    float hh = fmaxf(rby - lty, 0.0f);
                    float inter = ww * hh;
                    float iou = inter / (ai + aj - inter + 1e-9f);  // IEEE div, ref op order
                    s = iou > IOU_THR;
                }
                u64 m = __ballot(s);
                if (lane == (jb >> 6)) supw |= m;
            }
        }
    }
}

// ---------------- k4: emit [B,N,6] = det * keep (zeros elsewhere; d_out is poisoned)
__global__ void k4_out(const float* __restrict__ sdet,
                       const int* __restrict__ keep,
                       float* __restrict__ out) {
    int t = blockIdx.x * blockDim.x + threadIdx.x;
    if (t >= BN) return;
    const float* dr = sdet + (size_t)t * 8;
    float* o = out + (size_t)t * 6;
    if (keep[t]) {
        o[0] = dr[0]; o[1] = dr[1]; o[2] = dr[2];
        o[3] = dr[3]; o[4] = dr[4]; o[5] = dr[5];
    } else {
        o[0] = 0.0f; o[1] = 0.0f; o[2] = 0.0f;
        o[3] = 0.0f; o[4] = 0.0f; o[5] = 0.0f;
    }
}

extern "C" void kernel_launch(void* const* d_in, const int* in_sizes, int n_in,
                              void* d_out, int out_size, void* d_ws, size_t ws_size,
                              hipStream_t stream) {
    const float* boxes      = (const float*)d_in[0];   // [B,N,4]
    const float* box_scores = (const float*)d_in[1];   // [B,N]
    const float* cls_preds  = (const float*)d_in[2];   // [B,N,C]

    char* ws = (char*)d_ws;
    size_t off = 0;
    float4* boxes_c = (float4*)(ws + off); off += (size_t)BN * 16;      // 256 KB
    float4* sobox   = (float4*)(ws + off); off += (size_t)BN * 16;      // 256 KB
    float*  sdet    = (float*)(ws + off);  off += (size_t)BN * 8 * 4;   // 512 KB
    u64*    keys    = (u64*)(ws + off);    off += (size_t)BN * 8;       // 128 KB
    float*  conf    = (float*)(ws + off);  off += (size_t)BN * 4;       //  64 KB
    int*    clsval  = (int*)(ws + off);    off += (size_t)BN * 4;       //  64 KB
    int*    sclsv   = (int*)(ws + off);    off += (size_t)BN * 4;       //  64 KB
    int*    keep    = (int*)(ws + off);    off += (size_t)BN * 4;       //  64 KB  (~1.4 MB total)

    k1_score<<<BN / 256, 256, 0, stream>>>(boxes, box_scores, cls_preds,
                                           boxes_c, conf, clsval, keys);
    k2_sort<<<BB, 1024, 0, stream>>>(keys, boxes_c, conf, clsval,
                                     sobox, sdet, sclsv, keep);
    k3_nms<<<BB * CC, 64, 0, stream>>>(sobox, sclsv, keep);
    k4_out<<<BN / 256, 256, 0, stream>>>(sdet, keep, (float*)d_out);
}

// Round 3
// 121.937 us; speedup vs baseline: 1.5798x; 1.5798x over previous
//
#include <hip/hip_runtime.h>
#include <stdint.h>

// Bitwise reproducibility vs the numpy reference: forbid a*b+c fusion so every
// mul/add rounds exactly like the ref (keep-decision booleans must not flip).
#pragma clang fp contract(off)

typedef unsigned long long u64;
typedef unsigned int u32;

namespace {
constexpr int BB = 4;
constexpr int NN = 4096;
constexpr int CC = 64;
constexpr int BN = BB * NN;
constexpr float TARGET = 560.0f;
constexpr float MIN_BOX = 5.0f;
constexpr float IOU_THR = 0.2f;
constexpr float CONF_THR = 0.001f;
constexpr float BOX_CONF_THR = 0.01f;
constexpr float MAX_WH = 4096.0f;
constexpr int MAXK = 2048;   // per-(batch,class) capacity; data has ~64 +/- 8 per class
}

// ---------------- k1: clip, conf = max_c(cls_pred*score), argmax, valid,
// unique 44-bit sort key (score-map<<12 | reversed idx), zero the rank buffer.
__global__ __launch_bounds__(64) void k1_score(const float* __restrict__ boxes,
                                               const float* __restrict__ box_scores,
                                               const float* __restrict__ cls_preds,
                                               float4* __restrict__ boxes_c,
                                               float* __restrict__ conf,
                                               int* __restrict__ clsval,
                                               u64* __restrict__ key64,
                                               int* __restrict__ rank) {
    int t = blockIdx.x * 64 + threadIdx.x;   // grid exactly covers BN
    float4 bx = ((const float4*)boxes)[t];
    float x1 = fminf(fmaxf(bx.x, 0.0f), TARGET);
    float y1 = fminf(fmaxf(bx.y, 0.0f), TARGET);
    float x2 = fminf(fmaxf(bx.z, 0.0f), TARGET);
    float y2 = fminf(fmaxf(bx.w, 0.0f), TARGET);
    float w = x2 - x1, h = y2 - y1;
    float bs = box_scores[t];
    const float4* cp = (const float4*)(cls_preds + (size_t)t * CC);
    float best = -1.0f;   // products >= 0, so element 0 always beats init
    int bestc = 0;
#pragma unroll
    for (int q = 0; q < CC / 4; ++q) {
        float4 v = cp[q];
        float p0 = v.x * bs, p1 = v.y * bs, p2 = v.z * bs, p3 = v.w * bs;
        // strict > preserves numpy first-occurrence argmax semantics
        if (p0 > best) { best = p0; bestc = q * 4 + 0; }
        if (p1 > best) { best = p1; bestc = q * 4 + 1; }
        if (p2 > best) { best = p2; bestc = q * 4 + 2; }
        if (p3 > best) { best = p3; bestc = q * 4 + 3; }
    }
    bool valid = (bs > BOX_CONF_THR) && (w > MIN_BOX) && (h > MIN_BOX) && (best > CONF_THR);
    float sk = valid ? best : -1.0f;
    // monotonic float->uint map (ascending). Unique key: ties (all invalid at -1.0)
    // break toward smaller original index ranking first => stable descending sort.
    unsigned fb = __float_as_uint(sk);
    unsigned mm = (fb & 0x80000000u) ? ~fb : (fb | 0x80000000u);
    int i = t & (NN - 1);
    key64[t] = ((u64)mm << 12) | (u64)(NN - 1 - i);
    float4 bc; bc.x = x1; bc.y = y1; bc.z = x2; bc.w = y2;
    boxes_c[t] = bc;
    conf[t] = best;
    clsval[t] = bestc | (valid ? 0x10000 : 0);
    rank[t] = 0;   // k2_rank accumulates with atomics
}

// ---------------- k2a: rank by counting. rank_i = #{j in batch: key_j > key_i}.
// Scan split 4 ways per element across blocks; exact int atomic accumulation.
// 256 blocks x 256 thr: ~1024 waves over 256 CUs, ~4µs of u64 compares.
__global__ __launch_bounds__(256) void k2_rank(const u64* __restrict__ key64,
                                               int* __restrict__ rank) {
    __shared__ u64 sk[1024];   // 8 KB: this block's key chunk
    int bid = blockIdx.x;
    int kseg = bid & 3;          // which 1024-key chunk we scan
    int eseg = (bid >> 2) & 15;  // which 256 elements we own
    int b    = bid >> 6;
    int tid = threadIdx.x;
    const u64* kb = key64 + (size_t)b * NN;
    for (int p = tid; p < 1024; p += 256) sk[p] = kb[kseg * 1024 + p];
    __syncthreads();
    int i = eseg * 256 + tid;
    u64 my = kb[i];
    int r = 0;
    const ulonglong2* s2 = (const ulonglong2*)sk;   // b128 broadcast reads, 2 keys each
#pragma unroll 8
    for (int q = 0; q < 512; ++q) {
        ulonglong2 v = s2[q];
        r += (int)(v.x > my) + (int)(v.y > my);
    }
    atomicAdd(&rank[b * NN + i], r);
}

// ---------------- k2b: scatter into sorted order (dst = rank): offset boxes for
// IoU, det rows for output, class|valid tags.
__global__ __launch_bounds__(64) void k2_scatter(const int* __restrict__ rank,
                                                 const float4* __restrict__ boxes_c,
                                                 const float* __restrict__ conf,
                                                 const int* __restrict__ clsval,
                                                 float4* __restrict__ sobox,
                                                 float4* __restrict__ sdet,
                                                 int* __restrict__ sclsv) {
    int t = blockIdx.x * 64 + threadIdx.x;
    int b = t >> 12;
    int dst = (b << 12) + rank[t];
    float4 bc = boxes_c[t];
    int cv = clsval[t];
    int c = cv & 0xFF;
    int valid = (cv >> 16) & 1;
    float off = (float)c * MAX_WH;   // exact (c*2^12); the + is the ref's one rounding
    float4 ob; ob.x = bc.x + off; ob.y = bc.y + off; ob.z = bc.z + off; ob.w = bc.w + off;
    sobox[dst] = ob;
    sdet[(size_t)dst * 2] = bc;
    float4 d1; d1.x = conf[t]; d1.y = (float)c; d1.z = 0.0f; d1.w = 0.0f;
    sdet[(size_t)dst * 2 + 1] = d1;
    sclsv[dst] = c | (valid << 8);
}

__device__ inline void zero_row(float* __restrict__ out, int p) {
    float2* o2 = (float2*)(out + (size_t)p * 6);   // p*24B is 8B-aligned
    float2 z; z.x = 0.0f; z.y = 0.0f;
    o2[0] = z; o2[1] = z; o2[2] = z;
}

// ---------------- k3: one wave per (batch,class). Cross-class IoU is exactly 0
// (offset >= 4096 > any extent), so global greedy NMS == independent per-class
// greedy in sorted order. This block OWNS every sorted position whose argmax
// class == myc: invalid -> zero row (during compaction), suppressed -> zero row,
// kept -> det row. Full coverage of d_out (poisoned 0xAA each call).
__global__ __launch_bounds__(64) void k3_nms(const float4* __restrict__ sobox,
                                             const int* __restrict__ sclsv,
                                             const float* __restrict__ sdet,
                                             float* __restrict__ out) {
    __shared__ float4 lbox[MAXK];   // 32 KB
    __shared__ int lpos[MAXK];      //  8 KB (grid=256 -> 1 block/CU; LDS is free real estate)
    int b = blockIdx.x >> 6;
    int myc = blockIdx.x & 63;
    int lane = threadIdx.x;
    int base0 = b * NN;
    // --- order-preserving compaction: int4 loads, per-lane popc, shfl prefix-scan ---
    int k = 0;
    for (int base = 0; base < NN; base += 256) {
        int pp = base + lane * 4;
        int4 cv = *(const int4*)(sclsv + base0 + pp);
        unsigned m4 = 0;
        {
            bool mt = (cv.x & 0xFF) == myc;
            if (mt) { if ((cv.x >> 8) & 1) m4 |= 1u; else zero_row(out, base0 + pp + 0); }
        }
        {
            bool mt = (cv.y & 0xFF) == myc;
            if (mt) { if ((cv.y >> 8) & 1) m4 |= 2u; else zero_row(out, base0 + pp + 1); }
        }
        {
            bool mt = (cv.z & 0xFF) == myc;
            if (mt) { if ((cv.z >> 8) & 1) m4 |= 4u; else zero_row(out, base0 + pp + 2); }
        }
        {
            bool mt = (cv.w & 0xFF) == myc;
            if (mt) { if ((cv.w >> 8) & 1) m4 |= 8u; else zero_row(out, base0 + pp + 3); }
        }
        int cnt = __popc(m4);
        int incl = cnt;
#pragma unroll
        for (int d2 = 1; d2 < 64; d2 <<= 1) {
            int t2 = __shfl_up(incl, d2);
            if (lane >= d2) incl += t2;
        }
        int d = k + (incl - cnt);            // exclusive offset
        if (m4 & 1u) { if (d < MAXK) lpos[d] = pp + 0; else zero_row(out, base0 + pp + 0); d++; }
        if (m4 & 2u) { if (d < MAXK) lpos[d] = pp + 1; else zero_row(out, base0 + pp + 1); d++; }
        if (m4 & 4u) { if (d < MAXK) lpos[d] = pp + 2; else zero_row(out, base0 + pp + 2); d++; }
        if (m4 & 8u) { if (d < MAXK) lpos[d] = pp + 3; else zero_row(out, base0 + pp + 3); d++; }
        k += __shfl(incl, 63);
    }
    if (k > MAXK) k = MAXK;
    __syncthreads();
    for (int m = lane; m < k; m += 64) lbox[m] = sobox[base0 + lpos[m]];
    __syncthreads();
    // --- greedy NMS: suppression bitmask distributed over lanes (lane w owns word w) ---
    u64 supw = 0;
    for (int i = 0; i < k; ++i) {
        u64 wd = __shfl(supw, i >> 6);
        if (((wd >> (i & 63)) & 1ull) == 0ull) {
            float4 bi = lbox[i];   // broadcast LDS read
            float ai = (bi.z - bi.x) * (bi.w - bi.y);
            for (int jb = (i + 1) & ~63; jb < k; jb += 64) {
                int j = jb + lane;
                bool s = false;
                if (j > i && j < k) {
                    float4 bj = lbox[j];
                    float aj = (bj.z - bj.x) * (bj.w - bj.y);
                    float ltx = fmaxf(bi.x, bj.x);
                    float lty = fmaxf(bi.y, bj.y);
                    float rbx = fminf(bi.z, bj.z);
                    float rby = fminf(bi.w, bj.w);
                    float ww = fmaxf(rbx - ltx, 0.0f);
                    float hh = fmaxf(rby - lty, 0.0f);
                    float inter = ww * hh;
                    float iou = inter / (ai + aj - inter + 1e-9f);  // IEEE div, ref op order
                    s = iou > IOU_THR;
                }
                u64 m = __ballot(s);
                if (lane == (jb >> 6)) supw |= m;
            }
        }
    }
    // --- epilogue: kept -> det row, suppressed -> zero row (parallel, vector loads) ---
    for (int t = 0; t * 64 < k; ++t) {
        int m = t * 64 + lane;
        u64 wd = __shfl(supw, t);
        if (m < k) {
            int p = base0 + lpos[m];
            float2* o2 = (float2*)(out + (size_t)p * 6);
            if (((wd >> lane) & 1ull) == 0ull) {
                const float4* dr = (const float4*)(sdet + (size_t)p * 8);
                float4 d0 = dr[0];
                float4 d1 = dr[1];
                float2 a; a.x = d0.x; a.y = d0.y;
                float2 c2; c2.x = d0.z; c2.y = d0.w;
                float2 e; e.x = d1.x; e.y = d1.y;
                o2[0] = a; o2[1] = c2; o2[2] = e;
            } else {
                float2 z; z.x = 0.0f; z.y = 0.0f;
                o2[0] = z; o2[1] = z; o2[2] = z;
            }
        }
    }
}

extern "C" void kernel_launch(void* const* d_in, const int* in_sizes, int n_in,
                              void* d_out, int out_size, void* d_ws, size_t ws_size,
                              hipStream_t stream) {
    const float* boxes      = (const float*)d_in[0];   // [B,N,4]
    const float* box_scores = (const float*)d_in[1];   // [B,N]
    const float* cls_preds  = (const float*)d_in[2];   // [B,N,C]

    char* ws = (char*)d_ws;
    size_t off = 0;
    float4* boxes_c = (float4*)(ws + off); off += (size_t)BN * 16;      // 256 KB
    float4* sobox   = (float4*)(ws + off); off += (size_t)BN * 16;      // 256 KB
    float4* sdet    = (float4*)(ws + off); off += (size_t)BN * 32;      // 512 KB
    u64*    key64   = (u64*)(ws + off);    off += (size_t)BN * 8;       // 128 KB
    float*  conf    = (float*)(ws + off);  off += (size_t)BN * 4;       //  64 KB
    int*    clsval  = (int*)(ws + off);    off += (size_t)BN * 4;       //  64 KB
    int*    sclsv   = (int*)(ws + off);    off += (size_t)BN * 4;       //  64 KB
    int*    rank    = (int*)(ws + off);    off += (size_t)BN * 4;       //  64 KB  (~1.4 MB)

    k1_score<<<BN / 64, 64, 0, stream>>>(boxes, box_scores, cls_preds,
                                         boxes_c, conf, clsval, key64, rank);
    k2_rank<<<BB * 64, 256, 0, stream>>>(key64, rank);
    k2_scatter<<<BN / 64, 64, 0, stream>>>(rank, boxes_c, conf, clsval,
                                           sobox, sdet, sclsv);
    k3_nms<<<BB * CC, 64, 0, stream>>>(sobox, sclsv, (const float*)sdet, (float*)d_out);
}